// Round 10
// baseline (213.396 us; speedup 1.0000x reference)
//
#include <hip/hip_runtime.h>

// CrissCrossAttention on MI355X. Input dtype (fp32 vs bf16) detected at
// runtime; internal compute fp32 with bf16 MFMA operands.
// B=4, C=64, CQ=8, H=W=128.
//
// R16: R15 base + (a) combine split to per-channel blocks (8192 blocks,
// 1 barrier, inv computed per-thread from L2-resident lRow/lCol -- the
// R13 qkv-split pattern, the only repeatable structural win), and
// (b) pv K-fragments hoisted out of the jt loop (4 serial HBM round-trips
// -> 1 batch; fits the 84-VGPR cap with R15's nb-split acc).

#define NE 4194304ull   // B*C*H*W elements per image tensor

typedef __attribute__((ext_vector_type(8))) short short8;
typedef __attribute__((ext_vector_type(4))) float f32x4;
typedef __attribute__((ext_vector_type(16))) float f32x16;

#define HD __device__ __forceinline__

HD float b2f(unsigned short u) { union { unsigned int i; float f; } v; v.i = ((unsigned int)u) << 16; return v.f; }
HD unsigned short f2b(float x) {
  union { float f; unsigned int i; } v; v.f = x;
  unsigned int r = v.i + 0x7FFFu + ((v.i >> 16) & 1u);
  return (unsigned short)(r >> 16);
}
HD unsigned int pk2(float a, float b) {
  return (unsigned int)f2b(a) | ((unsigned int)f2b(b) << 16);
}

// Abramowitz-Stegun 7.1.26 erf approximation, |abs err| <= 1.5e-7.
HD float erf_fast(float x) {
  const float ax = fabsf(x);
  const float t = 1.0f / (1.0f + 0.3275911f * ax);
  const float poly = ((((1.061405429f*t - 1.453152027f)*t + 1.421413741f)*t
                       - 0.284496736f)*t + 0.254829592f)*t;
  const float y = 1.0f - poly * __expf(-ax*ax);
  return copysignf(y, x);
}

// read element i of src as bf16, canonicalizing from fp32 if f!=0
HD unsigned short ldbf(const void* s0, int i, int f) {
  return f ? f2b(((const float*)s0)[i]) : ((const unsigned short*)s0)[i];
}

// ---------------------------------------------------------------------------
// 0) Prelude (64 blocks): detect dtype (redundantly per block), canonicalize
//    params to bf16 wout, build wqkv[11][16][64] bf16 + wbias[11][16] f32
//    directly from sources. Mtiles: 0=qA | 1=kA,qB | 2=kB | 3-6=vA | 7-10=vB.
// ---------------------------------------------------------------------------
__global__ __launch_bounds__(256) void prelude_kernel(
    const void* x1,
    const void* wqA, const void* bqA, const void* wkA, const void* bkA,
    const void* wvA, const void* bvA, const void* wqB, const void* bqB,
    const void* wkB, const void* bkB, const void* wvB, const void* bvB,
    const void* wp, const void* bp, const void* gA, const void* gB,
    const void* bng, const void* bnb,
    int* flag, unsigned short* wout)
{
  __shared__ int s;
  if (threadIdx.x == 0) s = 0;
  __syncthreads();
  const float a = fabsf(b2f(((const unsigned short*)x1)[threadIdx.x]));
  if (a > 1000.0f) atomicOr(&s, 1);
  __syncthreads();
  const int f = s;
  if (blockIdx.x == 0 && threadIdx.x == 0) *flag = f;

  const void* srcs[18] = {wqA,bqA,wkA,bkA,wvA,bvA,wqB,bqB,wkB,bkB,wvB,bvB,wp,bp,gA,gB,bng,bnb};
  const int   ns[18]   = {512,  8,512,  8,4096, 64,512,  8,512,  8,4096, 64,4096,64, 1, 1, 64, 64};
  unsigned short* wqkv = wout + 14696;
  float* wbias = (float*)(wout + 25960);

  const int gstride = gridDim.x * 256;
  for (int idx = blockIdx.x*256 + threadIdx.x; idx < 26136; idx += gstride) {
    if (idx < 14690) {
      int off = idx, k2 = 0;
      while (off >= ns[k2]) { off -= ns[k2]; ++k2; }
      wout[idx] = ldbf(srcs[k2], off, f);
    } else if (idx >= 25960) {
      const int i3 = idx - 25960, mt = i3 >> 4, r = i3 & 15;
      float val = 0.0f;
      if (mt == 0)      { if (r < 8) val = b2f(ldbf(bqA, r, f)); }
      else if (mt == 1) { val = b2f((r < 8) ? ldbf(bkA, r, f) : ldbf(bqB, r - 8, f)); }
      else if (mt == 2) { if (r < 8) val = b2f(ldbf(bkB, r, f)); }
      else if (mt < 7)  { val = b2f(ldbf(bvA, (mt-3)*16 + r, f)); }
      else              { val = b2f(ldbf(bvB, (mt-7)*16 + r, f)); }
      wbias[i3] = val;
    } else if (idx >= 14696) {
      const int i2 = idx - 14696;
      const int mt = i2 >> 10, rem = i2 & 1023, r = rem >> 6, ci = rem & 63;
      unsigned short val = 0;
      if (mt == 0)      { if (r < 8) val = ldbf(wqA, r*64 + ci, f); }
      else if (mt == 1) { val = (r < 8) ? ldbf(wkA, r*64 + ci, f) : ldbf(wqB, (r-8)*64 + ci, f); }
      else if (mt == 2) { if (r < 8) val = ldbf(wkB, r*64 + ci, f); }
      else if (mt < 7)  { val = ldbf(wvA, ((mt-3)*16 + r)*64 + ci, f); }
      else              { val = ldbf(wvB, ((mt-7)*16 + r)*64 + ci, f); }
      wqkv[i2] = val;
    }
  }
}

// ---------------------------------------------------------------------------
// 1) QKV via MFMA. Grid (h=128, b=4) = 512 blocks, 1 h-row (128 pixels) per
//    block. X staged pixel-major in LDS [128][66]; each wave owns 2 ntiles
//    (32 pixels); 11 mtiles of 4 MFMAs with double-buffered S epilogue.
// ---------------------------------------------------------------------------
__global__ __launch_bounds__(256) void qkv_kernel(
    const void* __restrict__ x1v, const void* __restrict__ x2v, const int* __restrict__ flag,
    const unsigned short* __restrict__ wqkv, const float* __restrict__ wbias,
    unsigned short* __restrict__ q, unsigned short* __restrict__ k,
    unsigned short* __restrict__ v)
{
  const int h = blockIdx.x, b = blockIdx.y;
  const int tid = threadIdx.x, lane = tid & 63, w4 = tid >> 6;
  const int col = lane & 15, quad = lane >> 4;
  const int f32m = *flag;
  __shared__ __align__(16) char smem[16896];   // Xb[128][66] bf16, later S0/S1
  unsigned short* Xb = (unsigned short*)smem;
  unsigned short* S0 = (unsigned short*)smem;          // 16x132 bf16 = 4224B
  unsigned short* S1 = (unsigned short*)(smem + 4224);
  const size_t gb = (size_t)b*1048576 + (size_t)h*128;

  short8 Bc[2][4];   // [pass: 0=x1, 1=x2][nt2*2 + kstep]
  #pragma unroll
  for (int pass = 0; pass < 2; ++pass) {
    const void* xv = pass ? x2v : x1v;
    for (int t = tid; t < 1024; t += 256) {
      const int c = t >> 4, w8 = (t & 15)*8;
      const size_t a = gb + (size_t)c*16384 + w8;
      unsigned short vals[8];
      if (f32m) {
        const float* xf = (const float*)xv;
        const float4 f0 = *(const float4*)(xf + a);
        const float4 f1 = *(const float4*)(xf + a + 4);
        vals[0]=f2b(f0.x); vals[1]=f2b(f0.y); vals[2]=f2b(f0.z); vals[3]=f2b(f0.w);
        vals[4]=f2b(f1.x); vals[5]=f2b(f1.y); vals[6]=f2b(f1.z); vals[7]=f2b(f1.w);
      } else {
        const uint4 u = *(const uint4*)((const unsigned short*)xv + a);
        vals[0]=(unsigned short)(u.x & 0xffff); vals[1]=(unsigned short)(u.x >> 16);
        vals[2]=(unsigned short)(u.y & 0xffff); vals[3]=(unsigned short)(u.y >> 16);
        vals[4]=(unsigned short)(u.z & 0xffff); vals[5]=(unsigned short)(u.z >> 16);
        vals[6]=(unsigned short)(u.w & 0xffff); vals[7]=(unsigned short)(u.w >> 16);
      }
      #pragma unroll
      for (int i = 0; i < 8; ++i) Xb[(w8 + i)*66 + c] = vals[i];
    }
    __syncthreads();
    const unsigned int* U = (const unsigned int*)Xb;
    #pragma unroll
    for (int nt2 = 0; nt2 < 2; ++nt2)
      #pragma unroll
      for (int ks = 0; ks < 2; ++ks) {
        const int n = w4*32 + nt2*16 + col;
        const int base = n*33 + (ks*32 + quad*8)/2;
        union { unsigned int u32[4]; short8 s; } p;
        #pragma unroll
        for (int jj = 0; jj < 4; ++jj) p.u32[jj] = U[base + jj];
        Bc[pass][nt2*2 + ks] = p.s;
      }
    __syncthreads();
  }

  #pragma unroll
  for (int mt = 0; mt < 11; ++mt) {
    f32x4 acc[2];
    acc[0] = (f32x4){0.f, 0.f, 0.f, 0.f};
    acc[1] = acc[0];
    #pragma unroll
    for (int ks = 0; ks < 2; ++ks) {
      union { uint4 u; short8 s; } A;
      A.u = *(const uint4*)(wqkv + mt*1024 + col*64 + ks*32 + quad*8);
      #pragma unroll
      for (int nt2 = 0; nt2 < 2; ++nt2)
        acc[nt2] = __builtin_amdgcn_mfma_f32_16x16x32_bf16(
            A.s, (mt == 0) ? Bc[1][nt2*2 + ks] : Bc[0][nt2*2 + ks], acc[nt2], 0, 0, 0);
    }
    float bias[4];
    #pragma unroll
    for (int r = 0; r < 4; ++r) bias[r] = wbias[mt*16 + quad*4 + r];
    unsigned short* S = (mt & 1) ? S1 : S0;
    #pragma unroll
    for (int nt2 = 0; nt2 < 2; ++nt2)
      #pragma unroll
      for (int r = 0; r < 4; ++r) {
        const int row = quad*4 + r;
        const int nloc = w4*32 + nt2*16 + col;
        S[row*132 + nloc] = f2b(acc[nt2][r] + bias[r]);
      }
    __syncthreads();
    if (mt < 3) {
      if (tid < 128) {
        const int nloc = tid;
        const int pixg = h*128 + nloc;
        union { unsigned short u[8]; uint4 v4; } P;
        #pragma unroll
        for (int r = 0; r < 8; ++r) P.u[r] = S[r*132 + nloc];
        if (mt == 0) {
          *(uint4*)(q + ((size_t)b*16384 + pixg)*8) = P.v4;
        } else if (mt == 1) {
          *(uint4*)(k + ((size_t)b*16384 + pixg)*8) = P.v4;
          #pragma unroll
          for (int r = 0; r < 8; ++r) P.u[r] = S[(8 + r)*132 + nloc];
          *(uint4*)(q + ((size_t)(4 + b)*16384 + pixg)*8) = P.v4;
        } else {
          *(uint4*)(k + ((size_t)(4 + b)*16384 + pixg)*8) = P.v4;
        }
      }
    } else {
      const int vm = (mt >= 7) ? mt - 7 : mt - 3;
      const int z  = (mt >= 7) ? 4 + b : b;
      const int cl = tid >> 4, u = tid & 15;
      const int co = vm*16 + cl;
      const uint4 a0 = *(const uint4*)&S[cl*132 + u*8];
      *(uint4*)(v + ((size_t)(z*64 + co)*16384 + (size_t)h*128 + u*8) ) = a0;
    }
  }
}

// ---------------------------------------------------------------------------
// 2) v transpose: vT[z][c][w][h] = v[z][c][h][w]   (z = br*4+b)
// ---------------------------------------------------------------------------
__global__ __launch_bounds__(256) void transpose_v(
    const unsigned short* __restrict__ vStd, unsigned short* __restrict__ vT)
{
  const int tile = blockIdx.x, c = blockIdx.y, z = blockIdx.z;
  const int h0 = (tile & 3) * 32, w0 = (tile >> 2) * 32;
  const size_t base = ((size_t)z*64 + c) * 16384;
  __shared__ unsigned short T[32][33];
  const int tid = threadIdx.x;
  for (int idx = tid; idx < 1024; idx += 256) {
    const int r = idx >> 5, cc = idx & 31;
    T[r][cc] = vStd[base + (size_t)(h0 + r)*128 + (w0 + cc)];
  }
  __syncthreads();
  for (int idx = tid; idx < 1024; idx += 256) {
    const int r = idx >> 5, cc = idx & 31;
    vT[base + (size_t)(w0 + r)*128 + (h0 + cc)] = T[cc][r];
  }
}

// ---------------------------------------------------------------------------
// 3) PV via 32x32x16 MFMA, swapped S^T, register-resident P. R15 structure
//    (nb-split PV, single acc live) + K-frags hoisted upfront (kfr[4], one
//    batched HBM round-trip instead of 4 serial). Peak live ~75 VGPR,
//    __launch_bounds__(256,6) -> 84-VGPR cap.
// ---------------------------------------------------------------------------
__global__ __launch_bounds__(256, 6) void pv_kernel(
    const unsigned short* __restrict__ q, const unsigned short* __restrict__ k,
    const unsigned short* __restrict__ vStd, const unsigned short* __restrict__ vT,
    unsigned short* __restrict__ outBrH, unsigned short* __restrict__ oColH,
    float* __restrict__ lRow, float* __restrict__ lCol)
{
  const int X = blockIdx.x, b = blockIdx.y;
  const int br = blockIdx.z & 1, dir = blockIdx.z >> 1;
  const int tid = threadIdx.x, lane = tid & 63, w4 = tid >> 6;
  const int lm = lane & 31, l5 = lane >> 5;
  const int z = br*4 + b;
  const size_t b4h = (size_t)z * 128;
  __shared__ __align__(16) char smem[16384];   // Vl swizzled -> Dst bf16 swizzled

  // stage V early (XOR-swizzled 16B chunks); barrier deferred to B-frag reads
  const unsigned short* vsrc = dir ? vStd : vT;
  const size_t vbase = ((size_t)z*64)*16384 + (size_t)X*128;
  for (int t = tid; t < 1024; t += 256) {
    const int c = t >> 4, slot = t & 15;
    const uint4 d = *(const uint4*)(vsrc + vbase + (size_t)c*16384 + slot*8);
    *(uint4*)(smem + c*256 + ((slot*16) ^ ((c & 15) << 4))) = d;
  }

  // Q + all K fragments loaded upfront (one batched round-trip).
  const uint4 zero4 = {0u, 0u, 0u, 0u};
  short8 qfr, kfr[4];
  {
    union { uint4 u; short8 s; } cv;
    uint4 a = zero4;
    if (l5 == 0) {
      const int m = w4*32 + lm;
      const size_t pix = (b4h + (dir ? X : m))*128 + (dir ? m : X);
      a = *(const uint4*)(q + pix*8);
    }
    cv.u = a; qfr = cv.s;
    #pragma unroll
    for (int jt = 0; jt < 4; ++jt) {
      uint4 e = zero4;
      if (l5 == 0) {
        const int j = jt*32 + lm;
        const size_t pix = (b4h + (dir ? X : j))*128 + (dir ? j : X);
        e = *(const uint4*)(k + pix*8);
      }
      cv.u = e; kfr[jt] = cv.s;
    }
  }

  float lsum = 0.0f;
  unsigned int pka[4][4], pkb[4][4];   // [jt][r2]: bf16 pairs (e0,e1) and (e2,e3)
  #pragma unroll
  for (int jt = 0; jt < 4; ++jt) {
    f32x16 sacc = (f32x16){0.f,0.f,0.f,0.f,0.f,0.f,0.f,0.f,
                           0.f,0.f,0.f,0.f,0.f,0.f,0.f,0.f};
    sacc = __builtin_amdgcn_mfma_f32_32x32x16_bf16(kfr[jt], qfr, sacc, 0, 0, 0);
    #pragma unroll
    for (int r2 = 0; r2 < 4; ++r2) {
      float pv4[4];
      #pragma unroll
      for (int e = 0; e < 4; ++e) {
        const int jl = e + 8*r2 + 4*l5;        // j within 32-tile
        float p = 0.0f;
        if (dir || (jt != w4) || (jl != lm)) p = __expf(sacc[r2*4 + e]);
        lsum += p;
        pv4[e] = p;
      }
      pka[jt][r2] = pk2(pv4[0], pv4[1]);
      pkb[jt][r2] = pk2(pv4[2], pv4[3]);
    }
  }

  // l-sums: own 64 js + partner half
  lsum += __shfl_xor(lsum, 32);
  if (l5 == 0) {
    float* lOut = dir ? lRow : lCol;
    lOut[((size_t)z*128 + X)*128 + w4*32 + lm] = lsum;
  }

  __syncthreads();   // B1: Vl ready

  // PV: D[m][c] = sum_j P[m][j] V[c][j]; nb-split, single acc live.
  #pragma unroll
  for (int nb = 0; nb < 2; ++nb) {
    f32x16 acc = (f32x16){0.f,0.f,0.f,0.f,0.f,0.f,0.f,0.f,
                          0.f,0.f,0.f,0.f,0.f,0.f,0.f,0.f};
    const int c = nb*32 + lm;
    #pragma unroll
    for (int kb = 0; kb < 8; ++kb) {
      const int qq = kb & 1, jt = kb >> 1;
      const unsigned int ownA = l5 ? pka[jt][2*qq+1] : pka[jt][2*qq];
      const unsigned int ownB = l5 ? pkb[jt][2*qq+1] : pkb[jt][2*qq];
      const unsigned int sndA = l5 ? pka[jt][2*qq]   : pka[jt][2*qq+1];
      const unsigned int sndB = l5 ? pkb[jt][2*qq]   : pkb[jt][2*qq+1];
      const unsigned int rcvA = (unsigned int)__shfl_xor((int)sndA, 32);
      const unsigned int rcvB = (unsigned int)__shfl_xor((int)sndB, 32);
      union { unsigned int u[4]; short8 s; } t4;
      t4.u[0] = l5 ? rcvA : ownA;   // e0..1  (from l5src=0)
      t4.u[1] = l5 ? rcvB : ownB;   // e2..3
      t4.u[2] = l5 ? ownA : rcvA;   // e4..5  (from l5src=1)
      t4.u[3] = l5 ? ownB : rcvB;   // e6..7
      union { uint4 u; short8 s; } bv;
      bv.u = *(const uint4*)(smem + c*256 + (((kb*2 + l5)*16) ^ ((c & 15) << 4)));
      acc = __builtin_amdgcn_mfma_f32_32x32x16_bf16(t4.s, bv.s, acc, 0, 0, 0);
    }
    __syncthreads();   // all waves done reading Vl c in [nb*32, nb*32+32)
    #pragma unroll
    for (int r2 = 0; r2 < 4; ++r2) {
      uint2 u;
      u.x = pk2(acc[r2*4+0], acc[r2*4+1]);
      u.y = pk2(acc[r2*4+2], acc[r2*4+3]);
      const int mbyte = w4*64 + r2*16 + l5*8;   // (w4*32 + 8*r2 + 4*l5)*2
      *(uint2*)(smem + c*256 + (mbyte ^ ((c & 15) << 3))) = u;
    }
  }
  __syncthreads();

  unsigned short* dsth = dir ? outBrH : oColH;
  for (int t = tid; t < 2048; t += 256) {
    const int c = t >> 5, mc = t & 31;
    const uint2 u = *(const uint2*)(smem + c*256 + ((mc*8) ^ ((c & 15) << 3)));
    *(uint2*)(dsth + vbase + (size_t)c*16384 + mc*4) = u;
  }
}

// ---------------------------------------------------------------------------
// 4) combine + normalize (bf16 I/O), per-channel blocks:
//    out[z][c][h][w] = (outBr + oCol^T) / (lRow + lCol^T).
//    Grid (tile16, z8, c64) = 8192 blocks. oCol 32x32 tile staged/transposed
//    in LDS (1 barrier); inv computed per-thread from L2-resident lRow/lCol.
// ---------------------------------------------------------------------------
__global__ __launch_bounds__(256) void combine_kernel(
    const unsigned short* __restrict__ oColU, const float* __restrict__ lRow,
    const float* __restrict__ lCol, unsigned short* __restrict__ outBr)
{
  const int tile = blockIdx.x, z = blockIdx.y, c = blockIdx.z;
  const int h0 = (tile & 3) * 32, w0 = (tile >> 2) * 32;
  const int tid = threadIdx.x;
  __shared__ unsigned short T[32][33];     // oCol tile [w][h]
  const size_t lzb = (size_t)z * 16384;
  const size_t cbase = ((size_t)(z*64 + c))*16384;

  // stage oCol tile: row r = w0+r, 4 ushorts per thread (uint2)
  {
    const int r = tid >> 3, h4 = (tid & 7)*4;
    const uint2 vc = *(const uint2*)(oColU + cbase + (size_t)(w0 + r)*128 + h0 + h4);
    T[r][h4+0] = (unsigned short)(vc.x & 0xffff);
    T[r][h4+1] = (unsigned short)(vc.x >> 16);
    T[r][h4+2] = (unsigned short)(vc.y & 0xffff);
    T[r][h4+3] = (unsigned short)(vc.y >> 16);
  }
  __syncthreads();

  // each thread: pixel row h = tid>>3, 4 w's at w4
  const int h = tid >> 3, w4 = (tid & 7)*4;
  const float4 lr = *(const float4*)(lRow + lzb + (size_t)(h0 + h)*128 + w0 + w4);
  float lc0 = lCol[lzb + (size_t)(w0 + w4 + 0)*128 + h0 + h];
  float lc1 = lCol[lzb + (size_t)(w0 + w4 + 1)*128 + h0 + h];
  float lc2 = lCol[lzb + (size_t)(w0 + w4 + 2)*128 + h0 + h];
  float lc3 = lCol[lzb + (size_t)(w0 + w4 + 3)*128 + h0 + h];
  float4 iv;
  iv.x = 1.0f / (lr.x + lc0);
  iv.y = 1.0f / (lr.y + lc1);
  iv.z = 1.0f / (lr.z + lc2);
  iv.w = 1.0f / (lr.w + lc3);

  const size_t off = cbase + (size_t)(h0 + h)*128 + w0 + w4;
  const uint2 ov = *(const uint2*)(outBr + off);
  float o0 = b2f((unsigned short)(ov.x & 0xffff));
  float o1 = b2f((unsigned short)(ov.x >> 16));
  float o2 = b2f((unsigned short)(ov.y & 0xffff));
  float o3 = b2f((unsigned short)(ov.y >> 16));
  o0 = (o0 + b2f(T[w4+0][h])) * iv.x;
  o1 = (o1 + b2f(T[w4+1][h])) * iv.y;
  o2 = (o2 + b2f(T[w4+2][h])) * iv.z;
  o3 = (o3 + b2f(T[w4+3][h])) * iv.w;
  uint2 u;
  u.x = pk2(o0, o1);
  u.y = pk2(o2, o3);
  *(uint2*)(outBr + off) = u;
}

// ---------------------------------------------------------------------------
// 5) diff -> 1x1 conv via MFMA -> fast-erf GELU -> p (bf16), BN partials.
//    Grid (hp=256, b=4): 64-pixel tiles. diff staged bf16 pixel-major in
//    LDS [64 pix][66]; each wave owns one 16-row mtile of wp (A-frags),
//    4 nt x 2 ks = 8 MFMAs/wave. part layout unchanged (1024 slots).
// ---------------------------------------------------------------------------
__global__ __launch_bounds__(256) void proj_kernel(
    const unsigned short* __restrict__ outA, const unsigned short* __restrict__ outB,
    const unsigned short* __restrict__ wp, const unsigned short* __restrict__ bp,
    unsigned short* __restrict__ pbuf, float* __restrict__ part)
{
  const int hp = blockIdx.x, b = blockIdx.y;
  const int tid = threadIdx.x, lane = tid & 63, w4 = tid >> 6;
  const int col = lane & 15, quad = lane >> 4;
  __shared__ __align__(16) char smem[17408];
  unsigned short* Xb = (unsigned short*)smem;   // diff bf16 [64 pix][66]
  float* S = (float*)smem;                      // g f32 [64 ch][68]

  const size_t gb = (size_t)b*1048576 + (size_t)hp*64;
  for (int t = tid; t < 512; t += 256) {
    const int c = t >> 3, rem = t & 7;
    const size_t a = gb + (size_t)c*16384 + rem*8;
    const uint4 ua = *(const uint4*)(outA + a);
    const uint4 ub = *(const uint4*)(outB + a);
    const unsigned short* pa = (const unsigned short*)&ua;
    const unsigned short* pb = (const unsigned short*)&ub;
    const int n = rem*8;
    #pragma unroll
    for (int i = 0; i < 8; ++i)
      Xb[(n + i)*66 + c] = f2b(fabsf(b2f(pa[i]) - b2f(pb[i])));
  }
  __syncthreads();

  short8 Bc[8];
  const unsigned int* U = (const unsigned int*)Xb;
  #pragma unroll
  for (int nt = 0; nt < 4; ++nt)
    #pragma unroll
    for (int ks = 0; ks < 2; ++ks) {
      const int n = nt*16 + col;
      const int base = n*33 + (ks*32 + quad*8)/2;
      union { unsigned int u32[4]; short8 s; } p;
      #pragma unroll
      for (int jj = 0; jj < 4; ++jj) p.u32[jj] = U[base + jj];
      Bc[nt*2 + ks] = p.s;
    }
  __syncthreads();   // Xb dead; S takes over the LDS

  f32x4 acc[4];
  #pragma unroll
  for (int nt = 0; nt < 4; ++nt) acc[nt] = (f32x4){0.f, 0.f, 0.f, 0.f};
  #pragma unroll
  for (int ks = 0; ks < 2; ++ks) {
    union { uint4 u; short8 s; } A;
    A.u = *(const uint4*)(wp + (w4*16 + col)*64 + ks*32 + quad*8);
    #pragma unroll
    for (int nt = 0; nt < 4; ++nt)
      acc[nt] = __builtin_amdgcn_mfma_f32_16x16x32_bf16(A.s, Bc[nt*2 + ks], acc[nt], 0, 0, 0);
  }

  float sg1[4] = {0.f, 0.f, 0.f, 0.f}, sg2[4] = {0.f, 0.f, 0.f, 0.f};
  #pragma unroll
  for (int nt = 0; nt < 4; ++nt)
    #pragma unroll
    for (int r = 0; r < 4; ++r) {
      const float x = acc[nt][r] + b2f(bp[w4*16 + quad*4 + r]);
      const float g = 0.5f * x * (1.0f + erf_fast(x * 0.70710678118f));
      S[(w4*16 + quad*4 + r)*68 + nt*16 + col] = g;
      sg1[r] += g; sg2[r] += g*g;
    }
  const int slot = hp*4 + b;
  #pragma unroll
  for (int r = 0; r < 4; ++r) {
    float s1 = sg1[r], s2 = sg2[r];
    s1 += __shfl_xor(s1, 1); s1 += __shfl_xor(s1, 2);
    s1 += __shfl_xor(s1, 4); s1 += __shfl_xor(s1, 8);
    s2 += __shfl_xor(s2, 1); s2 += __shfl_xor(s2, 2);
    s2 += __shfl_xor(s2, 4); s2 += __shfl_xor(s2, 8);
    if (col == 0) {
      const int co = w4*16 + quad*4 + r;
      part[(size_t)co*1024 + slot] = s1;
      part[(size_t)(64 + co)*1024 + slot] = s2;
    }
  }
  __syncthreads();

  for (int t = tid; t < 1024; t += 256) {
    const int row = t >> 4, px4 = (t & 15)*4;
    const float* sp = &S[row*68 + px4];
    uint2 u;
    u.x = pk2(sp[0], sp[1]);
    u.y = pk2(sp[2], sp[3]);
    *(uint2*)(pbuf + (size_t)(b*64 + row)*16384 + hp*64 + px4) = u;
  }
}

// ---------------------------------------------------------------------------
// 5b) reduce per-block BN partials: bnAcc[stat] = sum_i part[stat][i]
// ---------------------------------------------------------------------------
__global__ __launch_bounds__(256) void reduce_kernel(
    const float* __restrict__ part, float* __restrict__ bnAcc)
{
  const int stat = blockIdx.x, tid = threadIdx.x;
  const float4 v = *(const float4*)(part + (size_t)stat*1024 + tid*4);
  float s = v.x + v.y + v.z + v.w;
  #pragma unroll
  for (int off = 32; off >= 1; off >>= 1) s += __shfl_xor(s, off);
  __shared__ float ws4[4];
  if ((tid & 63) == 0) ws4[tid >> 6] = s;
  __syncthreads();
  if (tid == 0) bnAcc[stat] = ws4[0] + ws4[1] + ws4[2] + ws4[3];
}

// ---------------------------------------------------------------------------
// 6) BN finalize + residuals, 4 elems/thread, dtype-adaptive I/O.
//    Combined attention maps and pbuf read as bf16.
// ---------------------------------------------------------------------------
__global__ __launch_bounds__(256) void final_kernel(
    const unsigned short* __restrict__ pbuf,
    const unsigned short* __restrict__ outAH, const unsigned short* __restrict__ outBH,
    const void* __restrict__ x1v, const void* __restrict__ x2v, const int* __restrict__ flag,
    const unsigned short* __restrict__ gA, const unsigned short* __restrict__ gB,
    const unsigned short* __restrict__ bng, const unsigned short* __restrict__ bnb,
    const float* __restrict__ bnAcc, void* __restrict__ outv)
{
  const int f32m = *flag;
  const int idx = (blockIdx.x * 256 + threadIdx.x) * 4;
  const int c = (idx >> 14) & 63;
  const float invN = 1.0f / 65536.0f;
  const float s1 = bnAcc[c], s2 = bnAcc[64 + c];
  const float mean = s1 * invN;
  const float var = s2 * invN - mean*mean;
  const float scale = rsqrtf(var + 1e-5f) * b2f(bng[c]);
  const float beta = b2f(bnb[c]);
  const float ga = b2f(gA[0]), gb = b2f(gB[0]);
  const uint2 uP = *(const uint2*)(pbuf + idx);
  const uint2 uA = *(const uint2*)(outAH + idx);
  const uint2 uB = *(const uint2*)(outBH + idx);
  float p[4] = { b2f((unsigned short)(uP.x & 0xffff)), b2f((unsigned short)(uP.x >> 16)),
                 b2f((unsigned short)(uP.y & 0xffff)), b2f((unsigned short)(uP.y >> 16)) };
  float a[4] = { b2f((unsigned short)(uA.x & 0xffff)), b2f((unsigned short)(uA.x >> 16)),
                 b2f((unsigned short)(uA.y & 0xffff)), b2f((unsigned short)(uA.y >> 16)) };
  float bb[4] = { b2f((unsigned short)(uB.x & 0xffff)), b2f((unsigned short)(uB.x >> 16)),
                  b2f((unsigned short)(uB.y & 0xffff)), b2f((unsigned short)(uB.y >> 16)) };
  float xa[4], xb[4];
  if (f32m) {
    const float4 t1 = *(const float4*)((const float*)x1v + idx);
    const float4 t2 = *(const float4*)((const float*)x2v + idx);
    xa[0]=t1.x; xa[1]=t1.y; xa[2]=t1.z; xa[3]=t1.w;
    xb[0]=t2.x; xb[1]=t2.y; xb[2]=t2.z; xb[3]=t2.w;
  } else {
    const uint2 x1u = *(const uint2*)((const unsigned short*)x1v + idx);
    const uint2 x2u = *(const uint2*)((const unsigned short*)x2v + idx);
    xa[0] = b2f((unsigned short)(x1u.x & 0xffff)); xa[1] = b2f((unsigned short)(x1u.x >> 16));
    xa[2] = b2f((unsigned short)(x1u.y & 0xffff)); xa[3] = b2f((unsigned short)(x1u.y >> 16));
    xb[0] = b2f((unsigned short)(x2u.x & 0xffff)); xb[1] = b2f((unsigned short)(x2u.x >> 16));
    xb[2] = b2f((unsigned short)(x2u.y & 0xffff)); xb[3] = b2f((unsigned short)(x2u.y >> 16));
  }
  float o1f[4], o2f[4];
  #pragma unroll
  for (int t = 0; t < 4; ++t) {
    const float nv = (p[t] - mean)*scale + beta;
    o1f[t] = ga*a[t] + xa[t] + nv;
    o2f[t] = gb*bb[t] + xb[t] + nv;
  }
  if (f32m) {
    float* of = (float*)outv;
    *(float4*)(of + idx)      = (float4){o1f[0], o1f[1], o1f[2], o1f[3]};
    *(float4*)(of + NE + idx) = (float4){o2f[0], o2f[1], o2f[2], o2f[3]};
  } else {
    unsigned short* oh = (unsigned short*)outv;
    uint2 u1, u2;
    u1.x = (unsigned int)f2b(o1f[0]) | ((unsigned int)f2b(o1f[1]) << 16);
    u1.y = (unsigned int)f2b(o1f[2]) | ((unsigned int)f2b(o1f[3]) << 16);
    u2.x = (unsigned int)f2b(o2f[0]) | ((unsigned int)f2b(o2f[1]) << 16);
    u2.y = (unsigned int)f2b(o2f[2]) | ((unsigned int)f2b(o2f[3]) << 16);
    *(uint2*)(oh + idx) = u1;
    *(uint2*)(oh + NE + idx) = u2;
  }
}

// ---------------------------------------------------------------------------
extern "C" void kernel_launch(void* const* d_in, const int* in_sizes, int n_in,
                              void* d_out, int out_size, void* d_ws, size_t ws_size,
                              hipStream_t stream)
{
  const void* x1  = d_in[0];
  const void* x2  = d_in[1];

  char* ws = (char*)d_ws;
  const size_t MB = 1048576ull;
  unsigned short* q     = (unsigned short*)(ws);                 // 2 MB   [z][pix][8] bf16
  unsigned short* kk    = (unsigned short*)(ws + 2*MB);          // 2 MB
  float* lRow           = (float*)(ws + 4*MB);                   // 512 KB [z][h][w]
  float* lCol           = (float*)(ws + 4*MB + 512*1024);        // 512 KB [z][w][h]
  unsigned short* vStd  = (unsigned short*)(ws + 6*MB);          // 16 MB  [z][C][H][W] bf16
  unsigned short* vT    = (unsigned short*)(ws + 22*MB);         // 16 MB  [z][C][W][H] bf16
  unsigned short* outBrH= (unsigned short*)(ws + 38*MB);         // 16 MB  [z][C][H][W] bf16
  unsigned short* oColH = (unsigned short*)(ws + 54*MB);         // 16 MB  [z][C][W][H] bf16
  unsigned short* pbuf  = (unsigned short*)(ws + 70*MB);         // 8 MB   bf16
  float* part           = (float*)(ws + 86*MB);                  // 512 KB
  float* bnAcc          = (float*)(ws + 102*MB);                 // 512 B
  int*   flag           = (int*)(ws + 102*MB + 512);             // 4 B
  unsigned short* wC    = (unsigned short*)(ws + 102*MB + 1024); // canonical params + wqkv + bias

  prelude_kernel<<<64, 256, 0, stream>>>(
      x1, d_in[2], d_in[3], d_in[4], d_in[5], d_in[6], d_in[7], d_in[8], d_in[9],
      d_in[10], d_in[11], d_in[12], d_in[13], d_in[16], d_in[17], d_in[14], d_in[15],
      d_in[18], d_in[19], flag, wC);
  qkv_kernel<<<dim3(128, 4), 256, 0, stream>>>(
      x1, x2, flag, wC + 14696, (const float*)(wC + 25960), q, kk, vStd);
  transpose_v<<<dim3(16, 64, 8), 256, 0, stream>>>(vStd, vT);
  pv_kernel<<<dim3(128, 4, 4), 256, 0, stream>>>(q, kk, vStd, vT, outBrH, oColH, lRow, lCol);
  combine_kernel<<<dim3(16, 8, 64), 256, 0, stream>>>(oColH, lRow, lCol, outBrH);
  proj_kernel<<<dim3(256, 4), 256, 0, stream>>>(outBrH, outBrH + NE, wC + 10400, wC + 14496, pbuf, part);
  reduce_kernel<<<128, 256, 0, stream>>>(part, bnAcc);
  final_kernel<<<4096, 256, 0, stream>>>(pbuf, outBrH, outBrH + NE, x1, x2, flag,
                                         wC + 14560, wC + 14561, wC + 14562, wC + 14626,
                                         bnAcc, d_out);
}

// Round 11
// 208.712 us; speedup vs baseline: 1.0224x; 1.0224x over previous
//
#include <hip/hip_runtime.h>

// CrissCrossAttention on MI355X. Input dtype (fp32 vs bf16) detected at
// runtime; internal compute fp32 with bf16 MFMA operands.
// B=4, C=64, CQ=8, H=W=128.
//
// R17 = exact revert to R15 (best measured: 210.5us). R16's two changes
// (combine per-channel split, pv K-hoist) regressed ~3us and are dropped.
// Kept stack: bf16 attention maps + bf16 pbuf (R8/R11), MFMA proj (R8),
// qkv 1-row split (R13), pv 32x32 S^T register-P with nb-split acc and
// (256,6) clamp (R15).

#define NE 4194304ull   // B*C*H*W elements per image tensor

typedef __attribute__((ext_vector_type(8))) short short8;
typedef __attribute__((ext_vector_type(4))) float f32x4;
typedef __attribute__((ext_vector_type(16))) float f32x16;

#define HD __device__ __forceinline__

HD float b2f(unsigned short u) { union { unsigned int i; float f; } v; v.i = ((unsigned int)u) << 16; return v.f; }
HD unsigned short f2b(float x) {
  union { float f; unsigned int i; } v; v.f = x;
  unsigned int r = v.i + 0x7FFFu + ((v.i >> 16) & 1u);
  return (unsigned short)(r >> 16);
}
HD unsigned int pk2(float a, float b) {
  return (unsigned int)f2b(a) | ((unsigned int)f2b(b) << 16);
}

// Abramowitz-Stegun 7.1.26 erf approximation, |abs err| <= 1.5e-7.
HD float erf_fast(float x) {
  const float ax = fabsf(x);
  const float t = 1.0f / (1.0f + 0.3275911f * ax);
  const float poly = ((((1.061405429f*t - 1.453152027f)*t + 1.421413741f)*t
                       - 0.284496736f)*t + 0.254829592f)*t;
  const float y = 1.0f - poly * __expf(-ax*ax);
  return copysignf(y, x);
}

// read element i of src as bf16, canonicalizing from fp32 if f!=0
HD unsigned short ldbf(const void* s0, int i, int f) {
  return f ? f2b(((const float*)s0)[i]) : ((const unsigned short*)s0)[i];
}

// ---------------------------------------------------------------------------
// 0) Prelude (64 blocks): detect dtype (redundantly per block), canonicalize
//    params to bf16 wout, build wqkv[11][16][64] bf16 + wbias[11][16] f32
//    directly from sources. Mtiles: 0=qA | 1=kA,qB | 2=kB | 3-6=vA | 7-10=vB.
// ---------------------------------------------------------------------------
__global__ __launch_bounds__(256) void prelude_kernel(
    const void* x1,
    const void* wqA, const void* bqA, const void* wkA, const void* bkA,
    const void* wvA, const void* bvA, const void* wqB, const void* bqB,
    const void* wkB, const void* bkB, const void* wvB, const void* bvB,
    const void* wp, const void* bp, const void* gA, const void* gB,
    const void* bng, const void* bnb,
    int* flag, unsigned short* wout)
{
  __shared__ int s;
  if (threadIdx.x == 0) s = 0;
  __syncthreads();
  const float a = fabsf(b2f(((const unsigned short*)x1)[threadIdx.x]));
  if (a > 1000.0f) atomicOr(&s, 1);
  __syncthreads();
  const int f = s;
  if (blockIdx.x == 0 && threadIdx.x == 0) *flag = f;

  const void* srcs[18] = {wqA,bqA,wkA,bkA,wvA,bvA,wqB,bqB,wkB,bkB,wvB,bvB,wp,bp,gA,gB,bng,bnb};
  const int   ns[18]   = {512,  8,512,  8,4096, 64,512,  8,512,  8,4096, 64,4096,64, 1, 1, 64, 64};
  unsigned short* wqkv = wout + 14696;
  float* wbias = (float*)(wout + 25960);

  const int gstride = gridDim.x * 256;
  for (int idx = blockIdx.x*256 + threadIdx.x; idx < 26136; idx += gstride) {
    if (idx < 14690) {
      int off = idx, k2 = 0;
      while (off >= ns[k2]) { off -= ns[k2]; ++k2; }
      wout[idx] = ldbf(srcs[k2], off, f);
    } else if (idx >= 25960) {
      const int i3 = idx - 25960, mt = i3 >> 4, r = i3 & 15;
      float val = 0.0f;
      if (mt == 0)      { if (r < 8) val = b2f(ldbf(bqA, r, f)); }
      else if (mt == 1) { val = b2f((r < 8) ? ldbf(bkA, r, f) : ldbf(bqB, r - 8, f)); }
      else if (mt == 2) { if (r < 8) val = b2f(ldbf(bkB, r, f)); }
      else if (mt < 7)  { val = b2f(ldbf(bvA, (mt-3)*16 + r, f)); }
      else              { val = b2f(ldbf(bvB, (mt-7)*16 + r, f)); }
      wbias[i3] = val;
    } else if (idx >= 14696) {
      const int i2 = idx - 14696;
      const int mt = i2 >> 10, rem = i2 & 1023, r = rem >> 6, ci = rem & 63;
      unsigned short val = 0;
      if (mt == 0)      { if (r < 8) val = ldbf(wqA, r*64 + ci, f); }
      else if (mt == 1) { val = (r < 8) ? ldbf(wkA, r*64 + ci, f) : ldbf(wqB, (r-8)*64 + ci, f); }
      else if (mt == 2) { if (r < 8) val = ldbf(wkB, r*64 + ci, f); }
      else if (mt < 7)  { val = ldbf(wvA, ((mt-3)*16 + r)*64 + ci, f); }
      else              { val = ldbf(wvB, ((mt-7)*16 + r)*64 + ci, f); }
      wqkv[i2] = val;
    }
  }
}

// ---------------------------------------------------------------------------
// 1) QKV via MFMA. Grid (h=128, b=4) = 512 blocks, 1 h-row (128 pixels) per
//    block. X staged pixel-major in LDS [128][66]; each wave owns 2 ntiles
//    (32 pixels); 11 mtiles of 4 MFMAs with double-buffered S epilogue.
// ---------------------------------------------------------------------------
__global__ __launch_bounds__(256) void qkv_kernel(
    const void* __restrict__ x1v, const void* __restrict__ x2v, const int* __restrict__ flag,
    const unsigned short* __restrict__ wqkv, const float* __restrict__ wbias,
    unsigned short* __restrict__ q, unsigned short* __restrict__ k,
    unsigned short* __restrict__ v)
{
  const int h = blockIdx.x, b = blockIdx.y;
  const int tid = threadIdx.x, lane = tid & 63, w4 = tid >> 6;
  const int col = lane & 15, quad = lane >> 4;
  const int f32m = *flag;
  __shared__ __align__(16) char smem[16896];   // Xb[128][66] bf16, later S0/S1
  unsigned short* Xb = (unsigned short*)smem;
  unsigned short* S0 = (unsigned short*)smem;          // 16x132 bf16 = 4224B
  unsigned short* S1 = (unsigned short*)(smem + 4224);
  const size_t gb = (size_t)b*1048576 + (size_t)h*128;

  short8 Bc[2][4];   // [pass: 0=x1, 1=x2][nt2*2 + kstep]
  #pragma unroll
  for (int pass = 0; pass < 2; ++pass) {
    const void* xv = pass ? x2v : x1v;
    for (int t = tid; t < 1024; t += 256) {
      const int c = t >> 4, w8 = (t & 15)*8;
      const size_t a = gb + (size_t)c*16384 + w8;
      unsigned short vals[8];
      if (f32m) {
        const float* xf = (const float*)xv;
        const float4 f0 = *(const float4*)(xf + a);
        const float4 f1 = *(const float4*)(xf + a + 4);
        vals[0]=f2b(f0.x); vals[1]=f2b(f0.y); vals[2]=f2b(f0.z); vals[3]=f2b(f0.w);
        vals[4]=f2b(f1.x); vals[5]=f2b(f1.y); vals[6]=f2b(f1.z); vals[7]=f2b(f1.w);
      } else {
        const uint4 u = *(const uint4*)((const unsigned short*)xv + a);
        vals[0]=(unsigned short)(u.x & 0xffff); vals[1]=(unsigned short)(u.x >> 16);
        vals[2]=(unsigned short)(u.y & 0xffff); vals[3]=(unsigned short)(u.y >> 16);
        vals[4]=(unsigned short)(u.z & 0xffff); vals[5]=(unsigned short)(u.z >> 16);
        vals[6]=(unsigned short)(u.w & 0xffff); vals[7]=(unsigned short)(u.w >> 16);
      }
      #pragma unroll
      for (int i = 0; i < 8; ++i) Xb[(w8 + i)*66 + c] = vals[i];
    }
    __syncthreads();
    const unsigned int* U = (const unsigned int*)Xb;
    #pragma unroll
    for (int nt2 = 0; nt2 < 2; ++nt2)
      #pragma unroll
      for (int ks = 0; ks < 2; ++ks) {
        const int n = w4*32 + nt2*16 + col;
        const int base = n*33 + (ks*32 + quad*8)/2;
        union { unsigned int u32[4]; short8 s; } p;
        #pragma unroll
        for (int jj = 0; jj < 4; ++jj) p.u32[jj] = U[base + jj];
        Bc[pass][nt2*2 + ks] = p.s;
      }
    __syncthreads();
  }

  #pragma unroll
  for (int mt = 0; mt < 11; ++mt) {
    f32x4 acc[2];
    acc[0] = (f32x4){0.f, 0.f, 0.f, 0.f};
    acc[1] = acc[0];
    #pragma unroll
    for (int ks = 0; ks < 2; ++ks) {
      union { uint4 u; short8 s; } A;
      A.u = *(const uint4*)(wqkv + mt*1024 + col*64 + ks*32 + quad*8);
      #pragma unroll
      for (int nt2 = 0; nt2 < 2; ++nt2)
        acc[nt2] = __builtin_amdgcn_mfma_f32_16x16x32_bf16(
            A.s, (mt == 0) ? Bc[1][nt2*2 + ks] : Bc[0][nt2*2 + ks], acc[nt2], 0, 0, 0);
    }
    float bias[4];
    #pragma unroll
    for (int r = 0; r < 4; ++r) bias[r] = wbias[mt*16 + quad*4 + r];
    unsigned short* S = (mt & 1) ? S1 : S0;
    #pragma unroll
    for (int nt2 = 0; nt2 < 2; ++nt2)
      #pragma unroll
      for (int r = 0; r < 4; ++r) {
        const int row = quad*4 + r;
        const int nloc = w4*32 + nt2*16 + col;
        S[row*132 + nloc] = f2b(acc[nt2][r] + bias[r]);
      }
    __syncthreads();
    if (mt < 3) {
      if (tid < 128) {
        const int nloc = tid;
        const int pixg = h*128 + nloc;
        union { unsigned short u[8]; uint4 v4; } P;
        #pragma unroll
        for (int r = 0; r < 8; ++r) P.u[r] = S[r*132 + nloc];
        if (mt == 0) {
          *(uint4*)(q + ((size_t)b*16384 + pixg)*8) = P.v4;
        } else if (mt == 1) {
          *(uint4*)(k + ((size_t)b*16384 + pixg)*8) = P.v4;
          #pragma unroll
          for (int r = 0; r < 8; ++r) P.u[r] = S[(8 + r)*132 + nloc];
          *(uint4*)(q + ((size_t)(4 + b)*16384 + pixg)*8) = P.v4;
        } else {
          *(uint4*)(k + ((size_t)(4 + b)*16384 + pixg)*8) = P.v4;
        }
      }
    } else {
      const int vm = (mt >= 7) ? mt - 7 : mt - 3;
      const int z  = (mt >= 7) ? 4 + b : b;
      const int cl = tid >> 4, u = tid & 15;
      const int co = vm*16 + cl;
      const uint4 a0 = *(const uint4*)&S[cl*132 + u*8];
      *(uint4*)(v + ((size_t)(z*64 + co)*16384 + (size_t)h*128 + u*8) ) = a0;
    }
  }
}

// ---------------------------------------------------------------------------
// 2) v transpose: vT[z][c][w][h] = v[z][c][h][w]   (z = br*4+b)
// ---------------------------------------------------------------------------
__global__ __launch_bounds__(256) void transpose_v(
    const unsigned short* __restrict__ vStd, unsigned short* __restrict__ vT)
{
  const int tile = blockIdx.x, c = blockIdx.y, z = blockIdx.z;
  const int h0 = (tile & 3) * 32, w0 = (tile >> 2) * 32;
  const size_t base = ((size_t)z*64 + c) * 16384;
  __shared__ unsigned short T[32][33];
  const int tid = threadIdx.x;
  for (int idx = tid; idx < 1024; idx += 256) {
    const int r = idx >> 5, cc = idx & 31;
    T[r][cc] = vStd[base + (size_t)(h0 + r)*128 + (w0 + cc)];
  }
  __syncthreads();
  for (int idx = tid; idx < 1024; idx += 256) {
    const int r = idx >> 5, cc = idx & 31;
    vT[base + (size_t)(w0 + r)*128 + (h0 + cc)] = T[cc][r];
  }
}

// ---------------------------------------------------------------------------
// 3) PV via 32x32x16 MFMA, swapped S^T, register-resident P. R13 structure
//    with nb-split PV: one f32x16 acc live at a time (peak ~62 VGPR),
//    __launch_bounds__(256,6) -> 84-VGPR cap, 6 waves/SIMD.
//    nb=0 reads Vl c[0,32) then Dst-writes c[0,32) after a barrier (disjoint
//    from nb=1's Vl reads of c[32,64)); symmetric for nb=1; 4 barriers total.
// ---------------------------------------------------------------------------
__global__ __launch_bounds__(256, 6) void pv_kernel(
    const unsigned short* __restrict__ q, const unsigned short* __restrict__ k,
    const unsigned short* __restrict__ vStd, const unsigned short* __restrict__ vT,
    unsigned short* __restrict__ outBrH, unsigned short* __restrict__ oColH,
    float* __restrict__ lRow, float* __restrict__ lCol)
{
  const int X = blockIdx.x, b = blockIdx.y;
  const int br = blockIdx.z & 1, dir = blockIdx.z >> 1;
  const int tid = threadIdx.x, lane = tid & 63, w4 = tid >> 6;
  const int lm = lane & 31, l5 = lane >> 5;
  const int z = br*4 + b;
  const size_t b4h = (size_t)z * 128;
  __shared__ __align__(16) char smem[16384];   // Vl swizzled -> Dst bf16 swizzled

  // stage V early (XOR-swizzled 16B chunks); barrier deferred to B-frag reads
  const unsigned short* vsrc = dir ? vStd : vT;
  const size_t vbase = ((size_t)z*64)*16384 + (size_t)X*128;
  for (int t = tid; t < 1024; t += 256) {
    const int c = t >> 4, slot = t & 15;
    const uint4 d = *(const uint4*)(vsrc + vbase + (size_t)c*16384 + slot*8);
    *(uint4*)(smem + c*256 + ((slot*16) ^ ((c & 15) << 4))) = d;
  }

  // S^T phase: A = K (rows j, loaded per jt), B = Q (cols m). K-dim 8->16 pad.
  const uint4 zero4 = {0u, 0u, 0u, 0u};
  short8 qfr;
  {
    union { uint4 u; short8 s; } cv;
    uint4 a = zero4;
    if (l5 == 0) {
      const int m = w4*32 + lm;
      const size_t pix = (b4h + (dir ? X : m))*128 + (dir ? m : X);
      a = *(const uint4*)(q + pix*8);
    }
    cv.u = a; qfr = cv.s;
  }

  float lsum = 0.0f;
  unsigned int pka[4][4], pkb[4][4];   // [jt][r2]: bf16 pairs (e0,e1) and (e2,e3)
  #pragma unroll
  for (int jt = 0; jt < 4; ++jt) {
    union { uint4 u; short8 s; } kv;
    kv.u = zero4;
    if (l5 == 0) {
      const int j = jt*32 + lm;
      const size_t pix = (b4h + (dir ? X : j))*128 + (dir ? j : X);
      kv.u = *(const uint4*)(k + pix*8);
    }
    f32x16 sacc = (f32x16){0.f,0.f,0.f,0.f,0.f,0.f,0.f,0.f,
                           0.f,0.f,0.f,0.f,0.f,0.f,0.f,0.f};
    sacc = __builtin_amdgcn_mfma_f32_32x32x16_bf16(kv.s, qfr, sacc, 0, 0, 0);
    #pragma unroll
    for (int r2 = 0; r2 < 4; ++r2) {
      float pv4[4];
      #pragma unroll
      for (int e = 0; e < 4; ++e) {
        const int jl = e + 8*r2 + 4*l5;        // j within 32-tile
        float p = 0.0f;
        if (dir || (jt != w4) || (jl != lm)) p = __expf(sacc[r2*4 + e]);
        lsum += p;
        pv4[e] = p;
      }
      pka[jt][r2] = pk2(pv4[0], pv4[1]);
      pkb[jt][r2] = pk2(pv4[2], pv4[3]);
    }
  }

  // l-sums: own 64 js + partner half
  lsum += __shfl_xor(lsum, 32);
  if (l5 == 0) {
    float* lOut = dir ? lRow : lCol;
    lOut[((size_t)z*128 + X)*128 + w4*32 + lm] = lsum;
  }

  __syncthreads();   // B1: Vl ready

  // PV: D[m][c] = sum_j P[m][j] V[c][j]; nb-split, single acc live.
  #pragma unroll
  for (int nb = 0; nb < 2; ++nb) {
    f32x16 acc = (f32x16){0.f,0.f,0.f,0.f,0.f,0.f,0.f,0.f,
                          0.f,0.f,0.f,0.f,0.f,0.f,0.f,0.f};
    const int c = nb*32 + lm;
    #pragma unroll
    for (int kb = 0; kb < 8; ++kb) {
      const int qq = kb & 1, jt = kb >> 1;
      const unsigned int ownA = l5 ? pka[jt][2*qq+1] : pka[jt][2*qq];
      const unsigned int ownB = l5 ? pkb[jt][2*qq+1] : pkb[jt][2*qq];
      const unsigned int sndA = l5 ? pka[jt][2*qq]   : pka[jt][2*qq+1];
      const unsigned int sndB = l5 ? pkb[jt][2*qq]   : pkb[jt][2*qq+1];
      const unsigned int rcvA = (unsigned int)__shfl_xor((int)sndA, 32);
      const unsigned int rcvB = (unsigned int)__shfl_xor((int)sndB, 32);
      union { unsigned int u[4]; short8 s; } t4;
      t4.u[0] = l5 ? rcvA : ownA;   // e0..1  (from l5src=0)
      t4.u[1] = l5 ? rcvB : ownB;   // e2..3
      t4.u[2] = l5 ? ownA : rcvA;   // e4..5  (from l5src=1)
      t4.u[3] = l5 ? ownB : rcvB;   // e6..7
      union { uint4 u; short8 s; } bv;
      bv.u = *(const uint4*)(smem + c*256 + (((kb*2 + l5)*16) ^ ((c & 15) << 4)));
      acc = __builtin_amdgcn_mfma_f32_32x32x16_bf16(t4.s, bv.s, acc, 0, 0, 0);
    }
    __syncthreads();   // all waves done reading Vl c in [nb*32, nb*32+32)
    #pragma unroll
    for (int r2 = 0; r2 < 4; ++r2) {
      uint2 u;
      u.x = pk2(acc[r2*4+0], acc[r2*4+1]);
      u.y = pk2(acc[r2*4+2], acc[r2*4+3]);
      const int mbyte = w4*64 + r2*16 + l5*8;   // (w4*32 + 8*r2 + 4*l5)*2
      *(uint2*)(smem + c*256 + (mbyte ^ ((c & 15) << 3))) = u;
    }
  }
  __syncthreads();

  unsigned short* dsth = dir ? outBrH : oColH;
  for (int t = tid; t < 2048; t += 256) {
    const int c = t >> 5, mc = t & 31;
    const uint2 u = *(const uint2*)(smem + c*256 + ((mc*8) ^ ((c & 15) << 3)));
    *(uint2*)(dsth + vbase + (size_t)c*16384 + mc*4) = u;
  }
}

// ---------------------------------------------------------------------------
// 4) combine + normalize (bf16 I/O): out[z][c][h][w] =
//    (outBrU[z][c][h][w] + oColU[z][c][w][h]) / (lRow[z][h][w] + lCol[z][w][h])
//    Grid (tile16, z8, cg8): 8 channels per block.
// ---------------------------------------------------------------------------
__global__ __launch_bounds__(256) void combine_kernel(
    const unsigned short* __restrict__ oColU, const float* __restrict__ lRow,
    const float* __restrict__ lCol, unsigned short* __restrict__ outBr)
{
  const int tile = blockIdx.x, z = blockIdx.y, cg = blockIdx.z;
  const int h0 = (tile & 3) * 32, w0 = (tile >> 2) * 32, c0 = cg*8;
  const int tid = threadIdx.x;
  __shared__ float Tl[32][33];            // lCol tile [w][h]
  __shared__ __align__(16) float inv[32][36];   // [h][w]
  __shared__ __align__(16) float T4[4][32][36]; // oCol staging [ch][w][h]
  const size_t lzb = (size_t)z * 16384;
  {
    const int w = tid >> 3, h4 = (tid & 7)*4;
    const float4 vc = *(const float4*)(lCol + lzb + (size_t)(w0 + w)*128 + h0 + h4);
    Tl[w][h4+0] = vc.x; Tl[w][h4+1] = vc.y; Tl[w][h4+2] = vc.z; Tl[w][h4+3] = vc.w;
  }
  __syncthreads();
  {
    const int h = tid >> 3, w4 = (tid & 7)*4;
    const float4 lr = *(const float4*)(lRow + lzb + (size_t)(h0 + h)*128 + w0 + w4);
    float4 iv;
    iv.x = 1.0f / (lr.x + Tl[w4+0][h]);
    iv.y = 1.0f / (lr.y + Tl[w4+1][h]);
    iv.z = 1.0f / (lr.z + Tl[w4+2][h]);
    iv.w = 1.0f / (lr.w + Tl[w4+3][h]);
    *(float4*)&inv[h][w4] = iv;
  }
  __syncthreads();
  #pragma unroll
  for (int half = 0; half < 2; ++half) {
    for (int t = tid; t < 1024; t += 256) {
      const int ch = t >> 8, rem = t & 255, w = rem >> 3, h4 = (rem & 7)*4;
      const int c = c0 + half*4 + ch;
      const uint2 vc = *(const uint2*)(oColU + ((size_t)(z*64 + c))*16384
                                       + (size_t)(w0 + w)*128 + h0 + h4);
      float4 f;
      f.x = b2f((unsigned short)(vc.x & 0xffff)); f.y = b2f((unsigned short)(vc.x >> 16));
      f.z = b2f((unsigned short)(vc.y & 0xffff)); f.w = b2f((unsigned short)(vc.y >> 16));
      *(float4*)&T4[ch][w][h4] = f;
    }
    __syncthreads();
    for (int t = tid; t < 1024; t += 256) {
      const int ch = t >> 8, rem = t & 255, h = rem >> 3, w4 = (rem & 7)*4;
      const int c = c0 + half*4 + ch;
      const size_t off = ((size_t)(z*64 + c))*16384 + (size_t)(h0 + h)*128 + w0 + w4;
      const uint2 ov = *(const uint2*)(outBr + off);
      const float4 iv = *(const float4*)&inv[h][w4];
      float o0 = b2f((unsigned short)(ov.x & 0xffff));
      float o1 = b2f((unsigned short)(ov.x >> 16));
      float o2 = b2f((unsigned short)(ov.y & 0xffff));
      float o3 = b2f((unsigned short)(ov.y >> 16));
      o0 = (o0 + T4[ch][w4+0][h]) * iv.x;
      o1 = (o1 + T4[ch][w4+1][h]) * iv.y;
      o2 = (o2 + T4[ch][w4+2][h]) * iv.z;
      o3 = (o3 + T4[ch][w4+3][h]) * iv.w;
      uint2 u;
      u.x = (unsigned int)f2b(o0) | ((unsigned int)f2b(o1) << 16);
      u.y = (unsigned int)f2b(o2) | ((unsigned int)f2b(o3) << 16);
      *(uint2*)(outBr + off) = u;
    }
    __syncthreads();
  }
}

// ---------------------------------------------------------------------------
// 5) diff -> 1x1 conv via MFMA -> fast-erf GELU -> p (bf16), BN partials.
//    Grid (hp=256, b=4): 64-pixel tiles. diff staged bf16 pixel-major in
//    LDS [64 pix][66]; each wave owns one 16-row mtile of wp (A-frags),
//    4 nt x 2 ks = 8 MFMAs/wave. part layout unchanged (1024 slots).
// ---------------------------------------------------------------------------
__global__ __launch_bounds__(256) void proj_kernel(
    const unsigned short* __restrict__ outA, const unsigned short* __restrict__ outB,
    const unsigned short* __restrict__ wp, const unsigned short* __restrict__ bp,
    unsigned short* __restrict__ pbuf, float* __restrict__ part)
{
  const int hp = blockIdx.x, b = blockIdx.y;
  const int tid = threadIdx.x, lane = tid & 63, w4 = tid >> 6;
  const int col = lane & 15, quad = lane >> 4;
  __shared__ __align__(16) char smem[17408];
  unsigned short* Xb = (unsigned short*)smem;   // diff bf16 [64 pix][66]
  float* S = (float*)smem;                      // g f32 [64 ch][68]

  const size_t gb = (size_t)b*1048576 + (size_t)hp*64;
  for (int t = tid; t < 512; t += 256) {
    const int c = t >> 3, rem = t & 7;
    const size_t a = gb + (size_t)c*16384 + rem*8;
    const uint4 ua = *(const uint4*)(outA + a);
    const uint4 ub = *(const uint4*)(outB + a);
    const unsigned short* pa = (const unsigned short*)&ua;
    const unsigned short* pb = (const unsigned short*)&ub;
    const int n = rem*8;
    #pragma unroll
    for (int i = 0; i < 8; ++i)
      Xb[(n + i)*66 + c] = f2b(fabsf(b2f(pa[i]) - b2f(pb[i])));
  }
  __syncthreads();

  short8 Bc[8];
  const unsigned int* U = (const unsigned int*)Xb;
  #pragma unroll
  for (int nt = 0; nt < 4; ++nt)
    #pragma unroll
    for (int ks = 0; ks < 2; ++ks) {
      const int n = nt*16 + col;
      const int base = n*33 + (ks*32 + quad*8)/2;
      union { unsigned int u32[4]; short8 s; } p;
      #pragma unroll
      for (int jj = 0; jj < 4; ++jj) p.u32[jj] = U[base + jj];
      Bc[nt*2 + ks] = p.s;
    }
  __syncthreads();   // Xb dead; S takes over the LDS

  f32x4 acc[4];
  #pragma unroll
  for (int nt = 0; nt < 4; ++nt) acc[nt] = (f32x4){0.f, 0.f, 0.f, 0.f};
  #pragma unroll
  for (int ks = 0; ks < 2; ++ks) {
    union { uint4 u; short8 s; } A;
    A.u = *(const uint4*)(wp + (w4*16 + col)*64 + ks*32 + quad*8);
    #pragma unroll
    for (int nt = 0; nt < 4; ++nt)
      acc[nt] = __builtin_amdgcn_mfma_f32_16x16x32_bf16(A.s, Bc[nt*2 + ks], acc[nt], 0, 0, 0);
  }

  float sg1[4] = {0.f, 0.f, 0.f, 0.f}, sg2[4] = {0.f, 0.f, 0.f, 0.f};
  #pragma unroll
  for (int nt = 0; nt < 4; ++nt)
    #pragma unroll
    for (int r = 0; r < 4; ++r) {
      const float x = acc[nt][r] + b2f(bp[w4*16 + quad*4 + r]);
      const float g = 0.5f * x * (1.0f + erf_fast(x * 0.70710678118f));
      S[(w4*16 + quad*4 + r)*68 + nt*16 + col] = g;
      sg1[r] += g; sg2[r] += g*g;
    }
  const int slot = hp*4 + b;
  #pragma unroll
  for (int r = 0; r < 4; ++r) {
    float s1 = sg1[r], s2 = sg2[r];
    s1 += __shfl_xor(s1, 1); s1 += __shfl_xor(s1, 2);
    s1 += __shfl_xor(s1, 4); s1 += __shfl_xor(s1, 8);
    s2 += __shfl_xor(s2, 1); s2 += __shfl_xor(s2, 2);
    s2 += __shfl_xor(s2, 4); s2 += __shfl_xor(s2, 8);
    if (col == 0) {
      const int co = w4*16 + quad*4 + r;
      part[(size_t)co*1024 + slot] = s1;
      part[(size_t)(64 + co)*1024 + slot] = s2;
    }
  }
  __syncthreads();

  for (int t = tid; t < 1024; t += 256) {
    const int row = t >> 4, px4 = (t & 15)*4;
    const float* sp = &S[row*68 + px4];
    uint2 u;
    u.x = pk2(sp[0], sp[1]);
    u.y = pk2(sp[2], sp[3]);
    *(uint2*)(pbuf + (size_t)(b*64 + row)*16384 + hp*64 + px4) = u;
  }
}

// ---------------------------------------------------------------------------
// 5b) reduce per-block BN partials: bnAcc[stat] = sum_i part[stat][i]
// ---------------------------------------------------------------------------
__global__ __launch_bounds__(256) void reduce_kernel(
    const float* __restrict__ part, float* __restrict__ bnAcc)
{
  const int stat = blockIdx.x, tid = threadIdx.x;
  const float4 v = *(const float4*)(part + (size_t)stat*1024 + tid*4);
  float s = v.x + v.y + v.z + v.w;
  #pragma unroll
  for (int off = 32; off >= 1; off >>= 1) s += __shfl_xor(s, off);
  __shared__ float ws4[4];
  if ((tid & 63) == 0) ws4[tid >> 6] = s;
  __syncthreads();
  if (tid == 0) bnAcc[stat] = ws4[0] + ws4[1] + ws4[2] + ws4[3];
}

// ---------------------------------------------------------------------------
// 6) BN finalize + residuals, 4 elems/thread, dtype-adaptive I/O.
//    Combined attention maps and pbuf read as bf16.
// ---------------------------------------------------------------------------
__global__ __launch_bounds__(256) void final_kernel(
    const unsigned short* __restrict__ pbuf,
    const unsigned short* __restrict__ outAH, const unsigned short* __restrict__ outBH,
    const void* __restrict__ x1v, const void* __restrict__ x2v, const int* __restrict__ flag,
    const unsigned short* __restrict__ gA, const unsigned short* __restrict__ gB,
    const unsigned short* __restrict__ bng, const unsigned short* __restrict__ bnb,
    const float* __restrict__ bnAcc, void* __restrict__ outv)
{
  const int f32m = *flag;
  const int idx = (blockIdx.x * 256 + threadIdx.x) * 4;
  const int c = (idx >> 14) & 63;
  const float invN = 1.0f / 65536.0f;
  const float s1 = bnAcc[c], s2 = bnAcc[64 + c];
  const float mean = s1 * invN;
  const float var = s2 * invN - mean*mean;
  const float scale = rsqrtf(var + 1e-5f) * b2f(bng[c]);
  const float beta = b2f(bnb[c]);
  const float ga = b2f(gA[0]), gb = b2f(gB[0]);
  const uint2 uP = *(const uint2*)(pbuf + idx);
  const uint2 uA = *(const uint2*)(outAH + idx);
  const uint2 uB = *(const uint2*)(outBH + idx);
  float p[4] = { b2f((unsigned short)(uP.x & 0xffff)), b2f((unsigned short)(uP.x >> 16)),
                 b2f((unsigned short)(uP.y & 0xffff)), b2f((unsigned short)(uP.y >> 16)) };
  float a[4] = { b2f((unsigned short)(uA.x & 0xffff)), b2f((unsigned short)(uA.x >> 16)),
                 b2f((unsigned short)(uA.y & 0xffff)), b2f((unsigned short)(uA.y >> 16)) };
  float bb[4] = { b2f((unsigned short)(uB.x & 0xffff)), b2f((unsigned short)(uB.x >> 16)),
                  b2f((unsigned short)(uB.y & 0xffff)), b2f((unsigned short)(uB.y >> 16)) };
  float xa[4], xb[4];
  if (f32m) {
    const float4 t1 = *(const float4*)((const float*)x1v + idx);
    const float4 t2 = *(const float4*)((const float*)x2v + idx);
    xa[0]=t1.x; xa[1]=t1.y; xa[2]=t1.z; xa[3]=t1.w;
    xb[0]=t2.x; xb[1]=t2.y; xb[2]=t2.z; xb[3]=t2.w;
  } else {
    const uint2 x1u = *(const uint2*)((const unsigned short*)x1v + idx);
    const uint2 x2u = *(const uint2*)((const unsigned short*)x2v + idx);
    xa[0] = b2f((unsigned short)(x1u.x & 0xffff)); xa[1] = b2f((unsigned short)(x1u.x >> 16));
    xa[2] = b2f((unsigned short)(x1u.y & 0xffff)); xa[3] = b2f((unsigned short)(x1u.y >> 16));
    xb[0] = b2f((unsigned short)(x2u.x & 0xffff)); xb[1] = b2f((unsigned short)(x2u.x >> 16));
    xb[2] = b2f((unsigned short)(x2u.y & 0xffff)); xb[3] = b2f((unsigned short)(x2u.y >> 16));
  }
  float o1f[4], o2f[4];
  #pragma unroll
  for (int t = 0; t < 4; ++t) {
    const float nv = (p[t] - mean)*scale + beta;
    o1f[t] = ga*a[t] + xa[t] + nv;
    o2f[t] = gb*bb[t] + xb[t] + nv;
  }
  if (f32m) {
    float* of = (float*)outv;
    *(float4*)(of + idx)      = (float4){o1f[0], o1f[1], o1f[2], o1f[3]};
    *(float4*)(of + NE + idx) = (float4){o2f[0], o2f[1], o2f[2], o2f[3]};
  } else {
    unsigned short* oh = (unsigned short*)outv;
    uint2 u1, u2;
    u1.x = (unsigned int)f2b(o1f[0]) | ((unsigned int)f2b(o1f[1]) << 16);
    u1.y = (unsigned int)f2b(o1f[2]) | ((unsigned int)f2b(o1f[3]) << 16);
    u2.x = (unsigned int)f2b(o2f[0]) | ((unsigned int)f2b(o2f[1]) << 16);
    u2.y = (unsigned int)f2b(o2f[2]) | ((unsigned int)f2b(o2f[3]) << 16);
    *(uint2*)(oh + idx) = u1;
    *(uint2*)(oh + NE + idx) = u2;
  }
}

// ---------------------------------------------------------------------------
extern "C" void kernel_launch(void* const* d_in, const int* in_sizes, int n_in,
                              void* d_out, int out_size, void* d_ws, size_t ws_size,
                              hipStream_t stream)
{
  const void* x1  = d_in[0];
  const void* x2  = d_in[1];

  char* ws = (char*)d_ws;
  const size_t MB = 1048576ull;
  unsigned short* q     = (unsigned short*)(ws);                 // 2 MB   [z][pix][8] bf16
  unsigned short* kk    = (unsigned short*)(ws + 2*MB);          // 2 MB
  float* lRow           = (float*)(ws + 4*MB);                   // 512 KB [z][h][w]
  float* lCol           = (float*)(ws + 4*MB + 512*1024);        // 512 KB [z][w][h]
  unsigned short* vStd  = (unsigned short*)(ws + 6*MB);          // 16 MB  [z][C][H][W] bf16
  unsigned short* vT    = (unsigned short*)(ws + 22*MB);         // 16 MB  [z][C][W][H] bf16
  unsigned short* outBrH= (unsigned short*)(ws + 38*MB);         // 16 MB  [z][C][H][W] bf16
  unsigned short* oColH = (unsigned short*)(ws + 54*MB);         // 16 MB  [z][C][W][H] bf16
  unsigned short* pbuf  = (unsigned short*)(ws + 70*MB);         // 8 MB   bf16
  float* part           = (float*)(ws + 86*MB);                  // 512 KB
  float* bnAcc          = (float*)(ws + 102*MB);                 // 512 B
  int*   flag           = (int*)(ws + 102*MB + 512);             // 4 B
  unsigned short* wC    = (unsigned short*)(ws + 102*MB + 1024); // canonical params + wqkv + bias

  prelude_kernel<<<64, 256, 0, stream>>>(
      x1, d_in[2], d_in[3], d_in[4], d_in[5], d_in[6], d_in[7], d_in[8], d_in[9],
      d_in[10], d_in[11], d_in[12], d_in[13], d_in[16], d_in[17], d_in[14], d_in[15],
      d_in[18], d_in[19], flag, wC);
  qkv_kernel<<<dim3(128, 4), 256, 0, stream>>>(
      x1, x2, flag, wC + 14696, (const float*)(wC + 25960), q, kk, vStd);
  transpose_v<<<dim3(16, 64, 8), 256, 0, stream>>>(vStd, vT);
  pv_kernel<<<dim3(128, 4, 4), 256, 0, stream>>>(q, kk, vStd, vT, outBrH, oColH, lRow, lCol);
  combine_kernel<<<dim3(16, 8, 8), 256, 0, stream>>>(oColH, lRow, lCol, outBrH);
  proj_kernel<<<dim3(256, 4), 256, 0, stream>>>(outBrH, outBrH + NE, wC + 10400, wC + 14496, pbuf, part);
  reduce_kernel<<<128, 256, 0, stream>>>(part, bnAcc);
  final_kernel<<<4096, 256, 0, stream>>>(pbuf, outBrH, outBrH + NE, x1, x2, flag,
                                         wC + 14560, wC + 14561, wC + 14562, wC + 14626,
                                         bnAcc, d_out);
}